// Round 18
// baseline (143.127 us; speedup 1.0000x reference)
//
#include <hip/hip_runtime.h>
#include <stdint.h>
#include <stddef.h>

typedef _Float16 f16_t;
typedef _Float16 f16x4 __attribute__((ext_vector_type(4)));
typedef _Float16 f16x8 __attribute__((ext_vector_type(8)));
typedef float f32x4 __attribute__((ext_vector_type(4)));
typedef float f32x8 __attribute__((ext_vector_type(8)));
typedef float f32x16 __attribute__((ext_vector_type(16)));

#define AS_G __attribute__((address_space(1)))
#define AS_L __attribute__((address_space(3)))

__device__ __forceinline__ void gload_lds16(const void* g, void* l) {
  __builtin_amdgcn_global_load_lds((AS_G void*)g, (AS_L void*)l, 16, 0, 0);
}

#define FENCE() asm volatile("" ::: "memory")
#define BARX()                            \
  do {                                    \
    FENCE();                              \
    __builtin_amdgcn_s_barrier();         \
    FENCE();                              \
  } while (0)
#define VMCNT(n) asm volatile("s_waitcnt vmcnt(" #n ")" ::: "memory")
#define LGKM0() asm volatile("s_waitcnt lgkmcnt(0)" ::: "memory")
#if defined(__HIP_DEVICE_COMPILE__)
#define SCHEDB0() __builtin_amdgcn_sched_barrier(0)
#else
#define SCHEDB0()
#endif

// ---------------- dispatch 1: weight prep (frozen r17) ----------------

__global__ __launch_bounds__(256) void wprep_kernel(
    const float* __restrict__ Wo, const float* __restrict__ Wv,
    const float* __restrict__ bv, const float* __restrict__ bo,
    const float* __restrict__ nw, int Kw,
    f16_t* __restrict__ Wo_h, f16_t* __restrict__ WvT, float* __restrict__ bc) {
  __shared__ float smem[32 * 33];
  const int b = blockIdx.x;
  const int t = threadIdx.x;
  if (b < 1024) {
    const int i = b * 256 + t;
    f32x4 v = ((const f32x4*)Wo)[i];
    f16x4 o;
    o.x = (f16_t)v.x; o.y = (f16_t)v.y; o.z = (f16_t)v.z; o.w = (f16_t)v.w;
    ((f16x4*)Wo_h)[i] = o;
  } else if (b < 2048) {
    const int i = b - 1024;
    const int bx = i & 31, by = i >> 5;
    const int tx = t & 31, ty = t >> 5;
#pragma unroll
    for (int k = 0; k < 32; k += 8)
      smem[(ty + k) * 33 + tx] = Wv[(size_t)(by * 32 + ty + k) * 1024 + bx * 32 + tx];
    __syncthreads();
#pragma unroll
    for (int k = 0; k < 32; k += 8)
      WvT[(size_t)(bx * 32 + ty + k) * 1024 + by * 32 + tx] = (f16_t)smem[tx * 33 + ty + k];
  } else {
    const int e = b - 2048;
    float sw = 0.f;
    for (int k = 0; k < Kw; ++k) sw += nw[k];
    float p = 0.f;
    for (int d = t; d < 1024; d += 256) p += Wo[(size_t)e * 1024 + d] * bv[d];
    smem[t] = p;
    __syncthreads();
    for (int s = 128; s > 0; s >>= 1) {
      if (t < s) smem[t] += smem[t + s];
      __syncthreads();
    }
    if (t == 0) bc[e] = sw * smem[0] + bo[e];
  }
}

// ---------------- dispatch 2: WcT fast GEMM (hidden) || xavg 32-row (frozen r17) ----------------

__global__ __launch_bounds__(256) void xavg_wct_kernel(
    const float* __restrict__ X, const float* __restrict__ nw,
    const f16_t* __restrict__ Wo_h, const f16_t* __restrict__ WvT,
    f16_t* __restrict__ Xavg, f16_t* __restrict__ WcT) {
  __shared__ __align__(16) f16_t sAB[2 * 128 * 32];
  const int b = blockIdx.x;
  const int tid = threadIdx.x;

  if (b < 64) {
    constexpr int K = 1024, NN = 1024;
    f16_t* sA = sAB;
    f16_t* sB = sAB + 128 * 32;
    const int l = tid & 63;
    const int w = tid >> 6;
    const int wr = w >> 1;
    const int wc = w & 1;
    const int mt = b & 7;
    const int nt = b >> 3;
    const int m0 = mt << 7;
    const int n0 = nt << 7;

    const int srow = (w << 4) + (l >> 2);
    const int scol = (l & 3) << 3;
    const size_t aoff0 = (size_t)(m0 + srow) * K + scol;
    const size_t boff0 = (size_t)(n0 + srow) * K + scol;
    f16_t* ldsA = sA + (w << 9);
    f16_t* ldsB = sB + (w << 9);

    f32x4 acc[4][4];
#pragma unroll
    for (int i = 0; i < 4; ++i)
#pragma unroll
      for (int j = 0; j < 4; ++j) acc[i][j] = f32x4{0.f, 0.f, 0.f, 0.f};

    const int ka = (l >> 4) << 3;
    const int ar = (wr << 6) + (l & 15);
    const int br = (wc << 6) + (l & 15);

    for (int kt = 0; kt < (K >> 5); ++kt) {
      const int kb = kt << 5;
      gload_lds16(Wo_h + aoff0 + kb, ldsA);
      gload_lds16(Wo_h + aoff0 + ((size_t)K << 6) + kb, ldsA + 2048);
      gload_lds16(WvT + boff0 + kb, ldsB);
      gload_lds16(WvT + boff0 + ((size_t)K << 6) + kb, ldsB + 2048);
      __syncthreads();
      f16x8 af[4], bfr[4];
#pragma unroll
      for (int m = 0; m < 4; ++m) af[m] = *(const f16x8*)(sA + ((ar + (m << 4)) << 5) + ka);
#pragma unroll
      for (int n = 0; n < 4; ++n) bfr[n] = *(const f16x8*)(sB + ((br + (n << 4)) << 5) + ka);
#pragma unroll
      for (int m = 0; m < 4; ++m)
#pragma unroll
        for (int n = 0; n < 4; ++n)
          acc[m][n] = __builtin_amdgcn_mfma_f32_16x16x32_f16(af[m], bfr[n], acc[m][n], 0, 0, 0);
      __syncthreads();
    }

    const int orow = (l >> 4) << 2;
    const int ocol = l & 15;
#pragma unroll
    for (int n = 0; n < 4; ++n) {
      const int gn = n0 + (wc << 6) + (n << 4) + ocol;
#pragma unroll
      for (int m = 0; m < 4; ++m) {
        const int gm = m0 + (wr << 6) + (m << 4) + orow;
#pragma unroll
        for (int j = 0; j < 4; ++j)
          WcT[(size_t)(gm + j) * NN + gn] = (f16_t)acc[m][n][j];
      }
    }
  } else {
    const int T = 4096, D = 1024;
    const int R0 = (b - 64) * 32;
    const int half = tid >> 7;
    const int r0 = R0 + (half << 4);
    const int bb = (r0 >> 12) << 12;
    const int be = bb + T - 1;
    const int col = (tid & 127) << 3;
    const float w0 = nw[0], w1 = nw[1], w2 = nw[2];
    const float* xb = X + (size_t)r0 * D + col;
    f32x8 pp = *(const f32x8*)(xb + ((r0 == bb) ? 0 : -D));
    f32x8 pc = *(const f32x8*)(xb);
    f16_t* ob = Xavg + (size_t)r0 * D + col;
#pragma unroll
    for (int g = 0; g < 16; ++g) {
      f32x8 pn;
      if (r0 + g == be) pn = pc;
      else pn = *(const f32x8*)(xb + (size_t)(g + 1) * D);
      f32x8 y = w0 * pp + w1 * pc + w2 * pn;
      f16x8 o;
#pragma unroll
      for (int e = 0; e < 8; ++e) o[e] = (f16_t)y[e];
      *(f16x8*)(ob + (size_t)g * D) = o;
      pp = pc;
      pc = pn;
    }
  }
}

// ---------------- dispatch 3: 256^2 GEMM, 8-phase, now 32x32x16 MFMA ----------------
// Geometry/LDS/stages/vmcnt proof identical to r15/r17; only the fragment shape
// changes: per wave-tile 128x64 -> 4m x 2n frags of 32x32, K-step 16 (4 ks per
// BK=64). Phases = (m-half x n-half) quadrants of 8 MFMA. Read counts per phase
// (12/4/8/0 ds_read_b128) and chunk needs identical -> same certification.
// A frag: row = wr*128 + m*32 + (l&31), k0 = ks*16 + (l>>5)*8.
// B frag: row(Ncol) = wc*64 + n*32 + (l&31), same k mapping.
// C/D: col = l&31, row = (reg&3) + 8*(reg>>2) + 4*(l>>5)  [m74/m101].

__device__ __forceinline__ void stageA64(const f16_t* __restrict__ Ap, int K, int kt,
                                         int c, char* bufA, int w, int l) {
  const int f = w * 64 + l;
  const int sub = f >> 3, ch = f & 7;
  const int grow = ((c & 1) << 7) + ((c >> 1) << 6) + sub;
  const int gcol = (kt << 6) + ((ch ^ (sub & 7)) << 3);
  gload_lds16(Ap + (size_t)grow * K + gcol, bufA + c * 8192 + w * 1024);
}

__device__ __forceinline__ void stageB64(const f16_t* __restrict__ Bp, int K, int kt,
                                         int c, char* bufB, int w, int l) {
  const int f = w * 64 + l;
  const int rr = f >> 3, ch = f & 7;
  const int wc = ((c & 1) << 1) + (rr >> 5);
  const int sub = rr & 31;
  const int grow = (wc << 6) + ((c >> 1) << 5) + sub;
  const int gcol = (kt << 6) + ((ch ^ (sub & 7)) << 3);
  gload_lds16(Bp + (size_t)grow * K + gcol, bufB + c * 8192 + w * 1024);
}

__global__ __launch_bounds__(512, 2) void gemm8p_kernel(const f16_t* __restrict__ A,
                                                        const f16_t* __restrict__ Bt,
                                                        float* __restrict__ C,
                                                        const float* __restrict__ bias,
                                                        int M, int N, int K) {
  __shared__ __align__(16) char lds[2 * 65536];
  const int tid = threadIdx.x;
  const int l = tid & 63;
  const int w = tid >> 6;
  const int wr = w >> 2;
  const int wc = w & 3;
  const int l31 = l & 31;
  const int kg = l >> 5;        // k-group (8 of 16)
  const int x7 = l & 7;         // swizzle key (== lds row & 7 for all frag reads)

  const int cpx = (int)gridDim.x >> 3;
  const int swzb = ((int)blockIdx.x & 7) * cpx + ((int)blockIdx.x >> 3);
  const int nNT = N >> 8;
  const int mt = swzb / nNT;
  const int nt = swzb % nNT;
  const int m0 = mt << 8;
  const int n0 = nt << 8;

  const f16_t* Apanel = A + (size_t)m0 * K;
  const f16_t* Bpanel = Bt + (size_t)n0 * K;

  f32x16 acc[4][2];
#pragma unroll
  for (int m = 0; m < 4; ++m)
#pragma unroll
    for (int n = 0; n < 2; ++n)
#pragma unroll
      for (int e = 0; e < 16; ++e) acc[m][n][e] = 0.f;

  const int nT = K >> 6;

  f16x8 a0[2][4], a1[2][4], b0[4], b1[4];

  // A chunk (MH*2+wr): rows (within chunk) = mm*32 + l31 (mm in 0..1)
#define AREAD(DST, MH, BUF)                                                      \
  do {                                                                           \
    const char* p_ = (BUF) + (((MH)*2 + wr) << 13);                              \
    _Pragma("unroll") for (int mm = 0; mm < 2; ++mm)                             \
      _Pragma("unroll") for (int ks = 0; ks < 4; ++ks)                           \
        DST[mm][ks] = *(const f16x8*)(p_ + (((mm << 5) + l31) << 7) +            \
                                      ((((ks << 1) + kg) ^ x7) << 4));           \
  } while (0)
  // B: offset = NP*16384 + wc*4096 + l31*128 + swz-chunk
#define BREAD(DST, NP, BUF)                                                      \
  do {                                                                           \
    const char* p_ = (BUF) + 32768 + ((NP) << 14) + (wc << 12);                  \
    _Pragma("unroll") for (int ks = 0; ks < 4; ++ks)                             \
      DST[ks] = *(const f16x8*)(p_ + (l31 << 7) +                                \
                                ((((ks << 1) + kg) ^ x7) << 4));                 \
  } while (0)
#define PH_MFMA(MB, AR, NPB, BR)                                                 \
  do {                                                                           \
    __builtin_amdgcn_s_setprio(1);                                               \
    _Pragma("unroll") for (int mm = 0; mm < 2; ++mm)                             \
      _Pragma("unroll") for (int ks = 0; ks < 4; ++ks)                           \
        acc[(MB) + mm][NPB] = __builtin_amdgcn_mfma_f32_32x32x16_f16(            \
            AR[mm][ks], BR[ks], acc[(MB) + mm][NPB], 0, 0, 0);                   \
    __builtin_amdgcn_s_setprio(0);                                               \
  } while (0)

  // prologue: tile 0 -> buf0 in canonical order; establish invariant
  stageA64(Apanel, K, 0, 0, lds, w, l);
  stageB64(Bpanel, K, 0, 0, lds + 32768, w, l);
  stageA64(Apanel, K, 0, 1, lds, w, l);
  stageB64(Bpanel, K, 0, 1, lds + 32768, w, l);
  stageA64(Apanel, K, 0, 2, lds, w, l);
  stageB64(Bpanel, K, 0, 2, lds + 32768, w, l);
  stageA64(Apanel, K, 0, 3, lds, w, l);
  stageB64(Bpanel, K, 0, 3, lds + 32768, w, l);
  VMCNT(4);
  BARX();

  for (int tt = 0; tt < nT; ++tt) {
    char* cur = lds + (tt & 1) * 65536;
    char* nxtA = lds + ((tt + 1) & 1) * 65536;
    char* nxtB = nxtA + 32768;
    const int ktn = (tt + 1) < nT ? (tt + 1) : (nT - 1);

    // ---- phase 0: m0-1 x n0 ----
    AREAD(a0, 0, cur);
    BREAD(b0, 0, cur);
    stageA64(Apanel, K, ktn, 0, nxtA, w, l);
    stageB64(Bpanel, K, ktn, 0, nxtB, w, l);
    VMCNT(2);
    BARX();
    LGKM0();
    SCHEDB0();
    PH_MFMA(0, a0, 0, b0);
    BARX();

    // ---- phase 1: m0-1 x n1 ----
    BREAD(b1, 1, cur);
    stageA64(Apanel, K, ktn, 1, nxtA, w, l);
    stageB64(Bpanel, K, ktn, 1, nxtB, w, l);
    BARX();
    LGKM0();
    SCHEDB0();
    PH_MFMA(0, a0, 1, b1);
    BARX();

    // ---- phase 2: m2-3 x n0 ----
    AREAD(a1, 1, cur);
    stageA64(Apanel, K, ktn, 2, nxtA, w, l);
    stageB64(Bpanel, K, ktn, 2, nxtB, w, l);
    BARX();
    LGKM0();
    SCHEDB0();
    PH_MFMA(2, a1, 0, b0);
    BARX();

    // ---- phase 3: m2-3 x n1 ----
    stageA64(Apanel, K, ktn, 3, nxtA, w, l);
    stageB64(Bpanel, K, ktn, 3, nxtB, w, l);
    BARX();
    PH_MFMA(2, a1, 1, b1);
    VMCNT(4);
    BARX();
  }
#undef AREAD
#undef BREAD
#undef PH_MFMA

  // epilogue: 32x32 C/D layout: col = l31, row = (r&3) + 8*(r>>2) + 4*kg
  float bs2[2];
#pragma unroll
  for (int n = 0; n < 2; ++n) bs2[n] = bias[n0 + (wc << 6) + (n << 5) + l31];
#pragma unroll
  for (int m = 0; m < 4; ++m) {
#pragma unroll
    for (int n = 0; n < 2; ++n) {
      const int gn = n0 + (wc << 6) + (n << 5) + l31;
#pragma unroll
      for (int r = 0; r < 16; ++r) {
        const int row = (r & 3) + ((r >> 2) << 3) + (kg << 2);
        const int gm = m0 + (wr << 7) + (m << 5) + row;
        C[(size_t)gm * N + gn] = acc[m][n][r] + bs2[n];
      }
    }
  }
}

// ---------------- launch ----------------

extern "C" void kernel_launch(void* const* d_in, const int* in_sizes, int n_in,
                              void* d_out, int out_size, void* d_ws, size_t ws_size,
                              hipStream_t stream) {
  const float* x = (const float*)d_in[0];    // [8,4096,1024]
  const float* Wv = (const float*)d_in[1];   // [1024,1024]
  const float* bv = (const float*)d_in[2];   // [1024]
  const float* Wo = (const float*)d_in[3];   // [1024,1024]
  const float* bo = (const float*)d_in[4];   // [1024]
  const float* nw = (const float*)d_in[5];   // [3]
  float* out = (float*)d_out;

  char* ws = (char*)d_ws;
  f16_t* Wo_h = (f16_t*)(ws);                  // 2 MB
  f16_t* WvT  = (f16_t*)(ws + (2u << 20));     // 2 MB
  f16_t* WcT  = (f16_t*)(ws + (4u << 20));     // 2 MB (WcT = Wo @ Wv, [e][c])
  float* bc   = (float*)(ws + (6u << 20));     // 4 KB
  f16_t* Xavg = (f16_t*)(ws + (8u << 20));     // 64 MB

  wprep_kernel<<<dim3(3072), dim3(256), 0, stream>>>(
      Wo, Wv, bv, bo, nw, in_sizes[5], Wo_h, WvT, bc);
  xavg_wct_kernel<<<dim3(1088), dim3(256), 0, stream>>>(
      x, nw, Wo_h, WvT, Xavg, WcT);
  gemm8p_kernel<<<dim3(512), dim3(512), 0, stream>>>(
      Xavg, WcT, out, bc, 32768, 1024, 1024);
}

// Round 19
// 142.020 us; speedup vs baseline: 1.0078x; 1.0078x over previous
//
#include <hip/hip_runtime.h>
#include <stdint.h>
#include <stddef.h>

typedef _Float16 f16_t;
typedef _Float16 f16x4 __attribute__((ext_vector_type(4)));
typedef _Float16 f16x8 __attribute__((ext_vector_type(8)));
typedef float f32x4 __attribute__((ext_vector_type(4)));
typedef float f32x8 __attribute__((ext_vector_type(8)));

#define AS_G __attribute__((address_space(1)))
#define AS_L __attribute__((address_space(3)))

__device__ __forceinline__ void gload_lds16(const void* g, void* l) {
  __builtin_amdgcn_global_load_lds((AS_G void*)g, (AS_L void*)l, 16, 0, 0);
}

#define FENCE() asm volatile("" ::: "memory")
#define BARX()                            \
  do {                                    \
    FENCE();                              \
    __builtin_amdgcn_s_barrier();         \
    FENCE();                              \
  } while (0)
#define VMCNT(n) asm volatile("s_waitcnt vmcnt(" #n ")" ::: "memory")
#define LGKM0() asm volatile("s_waitcnt lgkmcnt(0)" ::: "memory")
#if defined(__HIP_DEVICE_COMPILE__)
#define SCHEDB0() __builtin_amdgcn_sched_barrier(0)
#else
#define SCHEDB0()
#endif

// ---------------- dispatch 1: merged prep ----------------
// blocks [0,64):      WcT = Wo @ Wv from RAW f32 (128^2 MFMA, LDS write-transpose;
//                     r14/r16-proven) — dispatched FIRST, hidden under xavg flood.
// blocks [64,1088):   bconst[e] = (sum w)*dot(Wo[e,:],bv) + bo[e]
// blocks [1088,2112): xavg 3-tap, 32 rows/block (2x16 rolling rows, r17-proven),
//                     f32x8 loads / f16x8 stores, read ratio 1.125x.

__global__ __launch_bounds__(256) void prep_kernel(
    const float* __restrict__ X, const float* __restrict__ Wo,
    const float* __restrict__ Wv, const float* __restrict__ bv,
    const float* __restrict__ bo, const float* __restrict__ nw, int Kw,
    f16_t* __restrict__ Xavg, f16_t* __restrict__ WcT, float* __restrict__ bc) {
  __shared__ __align__(16) f16_t sA[128 * 32];     // 8 KB  (WcT A tile)
  __shared__ __align__(16) float sWvT[128 * 36];   // 18 KB (WcT B^T tile, pad 36)
  __shared__ float smem[256];                      // 1 KB  (bconst)
  const int b = blockIdx.x;
  const int tid = threadIdx.x;

  if (b < 64) {
    // ---- WcT[e][c] = sum_d Wo[e][d]*Wv[d][c], raw f32 inputs, f16 out ----
    constexpr int K = 1024, NN = 1024;
    const int mt = b & 7, nt = b >> 3;
    const int m0 = mt << 7, n0 = nt << 7;
    const int l = tid & 63, w = tid >> 6;
    const int wr = w >> 1, wc = w & 1;
    const int q = l >> 4;
    const int ka = q << 3;
    const int ar = (wr << 6) + (l & 15);
    const int br = (wc << 6) + (l & 15);
    const int kS = tid >> 3;          // staging: k row 0..31
    const int cS = (tid & 7) << 4;    // staging: c base 0..112

    f32x4 acc[4][4];
#pragma unroll
    for (int i = 0; i < 4; ++i)
#pragma unroll
      for (int j = 0; j < 4; ++j) acc[i][j] = f32x4{0.f, 0.f, 0.f, 0.f};

    for (int kt = 0; kt < (K >> 5); ++kt) {
      const int kb = kt << 5;
      // A: Wo rows m0..m0+127, cols kb..kb+31 -> f16 [row][32]
#pragma unroll
      for (int i = 0; i < 2; ++i) {
        const int u = tid + i * 256;
        const int row = u >> 2, ch = u & 3;
        f32x8 v = *(const f32x8*)(Wo + (size_t)(m0 + row) * K + kb + ch * 8);
        f16x8 h;
#pragma unroll
        for (int e = 0; e < 8; ++e) h[e] = (f16_t)v[e];
        *(f16x8*)(sA + row * 32 + ch * 8) = h;
      }
      // B: Wv rows kb..kb+31, cols n0..n0+127 -> TRANSPOSED f32 [c][k], pad 36
#pragma unroll
      for (int j = 0; j < 4; ++j) {
        f32x4 v = *(const f32x4*)(Wv + (size_t)(kb + kS) * NN + n0 + cS + 4 * j);
#pragma unroll
        for (int i = 0; i < 4; ++i) sWvT[(cS + 4 * j + i) * 36 + kS] = v[i];
      }
      __syncthreads();
      f16x8 af[4], bfr[4];
#pragma unroll
      for (int m = 0; m < 4; ++m) af[m] = *(const f16x8*)(sA + (ar + (m << 4)) * 32 + ka);
#pragma unroll
      for (int n = 0; n < 4; ++n) {
        f32x4 v0 = *(const f32x4*)(sWvT + (br + (n << 4)) * 36 + ka);
        f32x4 v1 = *(const f32x4*)(sWvT + (br + (n << 4)) * 36 + ka + 4);
#pragma unroll
        for (int e = 0; e < 4; ++e) {
          bfr[n][e] = (f16_t)v0[e];
          bfr[n][e + 4] = (f16_t)v1[e];
        }
      }
#pragma unroll
      for (int m = 0; m < 4; ++m)
#pragma unroll
        for (int n = 0; n < 4; ++n)
          acc[m][n] = __builtin_amdgcn_mfma_f32_16x16x32_f16(af[m], bfr[n], acc[m][n], 0, 0, 0);
      __syncthreads();
    }

    const int orow = q << 2;
    const int ocol = l & 15;
#pragma unroll
    for (int n = 0; n < 4; ++n) {
      const int gn = n0 + (wc << 6) + (n << 4) + ocol;
#pragma unroll
      for (int m = 0; m < 4; ++m) {
        const int gm = m0 + (wr << 6) + (m << 4) + orow;
#pragma unroll
        for (int j = 0; j < 4; ++j)
          WcT[(size_t)(gm + j) * NN + gn] = (f16_t)acc[m][n][j];
      }
    }
  } else if (b < 1088) {
    // ---- bconst ----
    const int e = b - 64;
    float sw = 0.f;
    for (int k = 0; k < Kw; ++k) sw += nw[k];
    float p = 0.f;
    for (int d = tid; d < 1024; d += 256) p += Wo[(size_t)e * 1024 + d] * bv[d];
    smem[tid] = p;
    __syncthreads();
    for (int s = 128; s > 0; s >>= 1) {
      if (tid < s) smem[tid] += smem[tid + s];
      __syncthreads();
    }
    if (tid == 0) bc[e] = sw * smem[0] + bo[e];
  } else {
    // ---- xavg: 32 rows/block; 2 groups of 16 rolling rows; never straddles batch ----
    const int T = 4096, D = 1024;
    const int R0 = (b - 1088) * 32;
    const int half = tid >> 7;           // 0/1 -> rows [R0+16h, R0+16h+16)
    const int r0 = R0 + (half << 4);
    const int bb = (r0 >> 12) << 12;     // batch start
    const int be = bb + T - 1;           // batch end
    const int col = (tid & 127) << 3;    // 8-f32 column chunk
    const float w0 = nw[0], w1 = nw[1], w2 = nw[2];
    const float* xb = X + (size_t)r0 * D + col;
    f32x8 pp = *(const f32x8*)(xb + ((r0 == bb) ? 0 : -D));
    f32x8 pc = *(const f32x8*)(xb);
    f16_t* ob = Xavg + (size_t)r0 * D + col;
#pragma unroll
    for (int g = 0; g < 16; ++g) {
      f32x8 pn;
      if (r0 + g == be) pn = pc;
      else pn = *(const f32x8*)(xb + (size_t)(g + 1) * D);
      f32x8 y = w0 * pp + w1 * pc + w2 * pn;
      f16x8 o;
#pragma unroll
      for (int e = 0; e < 8; ++e) o[e] = (f16_t)y[e];
      *(f16x8*)(ob + (size_t)g * D) = o;
      pp = pc;
      pc = pn;
    }
  }
}

// ---------------- dispatch 2: 256^2 GEMM, 8-phase + counted vmcnt (r15/r17 frozen) ----------------
// out[M][N] = A[M][K]*Bt[N][K]^T + bias. 8 waves (2Mx4N), 16x16x32 MFMA, BK=64.
// 2x64KB dbuf; 4 phases/tile with 16 MFMA each; stages spread 2/phase in
// frag-prefix order; VMCNT(2) at ph0, VMCNT(4) at ph3 (never 0); XOR row
// swizzle both sides (2-way, free). Wait-invariant proof in r15 notes.

__device__ __forceinline__ void stageA64(const f16_t* __restrict__ Ap, int K, int kt,
                                         int c, char* bufA, int w, int l) {
  const int f = w * 64 + l;
  const int sub = f >> 3, ch = f & 7;
  const int grow = ((c & 1) << 7) + ((c >> 1) << 6) + sub;
  const int gcol = (kt << 6) + ((ch ^ (sub & 7)) << 3);
  gload_lds16(Ap + (size_t)grow * K + gcol, bufA + c * 8192 + w * 1024);
}

__device__ __forceinline__ void stageB64(const f16_t* __restrict__ Bp, int K, int kt,
                                         int c, char* bufB, int w, int l) {
  const int f = w * 64 + l;
  const int rr = f >> 3, ch = f & 7;
  const int wc = ((c & 1) << 1) + (rr >> 5);
  const int sub = rr & 31;
  const int grow = (wc << 6) + ((c >> 1) << 5) + sub;
  const int gcol = (kt << 6) + ((ch ^ (sub & 7)) << 3);
  gload_lds16(Bp + (size_t)grow * K + gcol, bufB + c * 8192 + w * 1024);
}

__global__ __launch_bounds__(512, 2) void gemm8p_kernel(const f16_t* __restrict__ A,
                                                        const f16_t* __restrict__ Bt,
                                                        float* __restrict__ C,
                                                        const float* __restrict__ bias,
                                                        int M, int N, int K) {
  __shared__ __align__(16) char lds[2 * 65536];
  const int tid = threadIdx.x;
  const int l = tid & 63;
  const int w = tid >> 6;
  const int wr = w >> 2;
  const int wc = w & 3;
  const int lr = l & 15;
  const int q = l >> 4;

  const int cpx = (int)gridDim.x >> 3;
  const int swzb = ((int)blockIdx.x & 7) * cpx + ((int)blockIdx.x >> 3);
  const int nNT = N >> 8;
  const int mt = swzb / nNT;
  const int nt = swzb % nNT;
  const int m0 = mt << 8;
  const int n0 = nt << 8;

  const f16_t* Apanel = A + (size_t)m0 * K;
  const f16_t* Bpanel = Bt + (size_t)n0 * K;

  const int x7 = lr & 7;

  f32x4 acc[8][4];
#pragma unroll
  for (int m = 0; m < 8; ++m)
#pragma unroll
    for (int n = 0; n < 4; ++n) acc[m][n] = f32x4{0.f, 0.f, 0.f, 0.f};

  const int nT = K >> 6;

  f16x8 a0[4][2], a1[4][2], b0[2][2], b1[2][2];

#define AREAD(DST, MH, BUF)                                                     \
  do {                                                                          \
    const char* p_ = (BUF) + (((MH)*2 + wr) << 13);                             \
    _Pragma("unroll") for (int mm = 0; mm < 4; ++mm)                            \
      _Pragma("unroll") for (int kk = 0; kk < 2; ++kk)                          \
        DST[mm][kk] = *(const f16x8*)(p_ + ((mm * 16 + lr) << 7) +              \
                                      ((((kk << 2) + q) ^ x7) << 4));           \
  } while (0)
#define BREAD(DST, NP, BUF)                                                     \
  do {                                                                          \
    const char* p_ = (BUF) + 32768 + ((((NP) << 2) + wc) << 12);                \
    _Pragma("unroll") for (int nn = 0; nn < 2; ++nn)                            \
      _Pragma("unroll") for (int kk = 0; kk < 2; ++kk)                          \
        DST[nn][kk] = *(const f16x8*)(p_ + ((nn * 16 + lr) << 7) +              \
                                      ((((kk << 2) + q) ^ x7) << 4));           \
  } while (0)
#define PH_MFMA(MB, AR, BR, NPB)                                                \
  do {                                                                          \
    __builtin_amdgcn_s_setprio(1);                                              \
    _Pragma("unroll") for (int mm = 0; mm < 4; ++mm)                            \
      _Pragma("unroll") for (int nn = 0; nn < 2; ++nn) {                        \
        acc[(MB) + mm][(NPB)*2 + nn] = __builtin_amdgcn_mfma_f32_16x16x32_f16(  \
            AR[mm][0], BR[nn][0], acc[(MB) + mm][(NPB)*2 + nn], 0, 0, 0);       \
        acc[(MB) + mm][(NPB)*2 + nn] = __builtin_amdgcn_mfma_f32_16x16x32_f16(  \
            AR[mm][1], BR[nn][1], acc[(MB) + mm][(NPB)*2 + nn], 0, 0, 0);       \
      }                                                                         \
    __builtin_amdgcn_s_setprio(0);                                              \
  } while (0)

  stageA64(Apanel, K, 0, 0, lds, w, l);
  stageB64(Bpanel, K, 0, 0, lds + 32768, w, l);
  stageA64(Apanel, K, 0, 1, lds, w, l);
  stageB64(Bpanel, K, 0, 1, lds + 32768, w, l);
  stageA64(Apanel, K, 0, 2, lds, w, l);
  stageB64(Bpanel, K, 0, 2, lds + 32768, w, l);
  stageA64(Apanel, K, 0, 3, lds, w, l);
  stageB64(Bpanel, K, 0, 3, lds + 32768, w, l);
  VMCNT(4);
  BARX();

  for (int tt = 0; tt < nT; ++tt) {
    char* cur = lds + (tt & 1) * 65536;
    char* nxtA = lds + ((tt + 1) & 1) * 65536;
    char* nxtB = nxtA + 32768;
    const int ktn = (tt + 1) < nT ? (tt + 1) : (nT - 1);

    // ---- phase 0 ----
    AREAD(a0, 0, cur);
    BREAD(b0, 0, cur);
    stageA64(Apanel, K, ktn, 0, nxtA, w, l);
    stageB64(Bpanel, K, ktn, 0, nxtB, w, l);
    VMCNT(2);
    BARX();
    LGKM0();
    SCHEDB0();
    PH_MFMA(0, a0, b0, 0);
    BARX();

    // ---- phase 1 ----
    BREAD(b1, 1, cur);
    stageA64(Apanel, K, ktn, 1, nxtA, w, l);
    stageB64(Bpanel, K, ktn, 1, nxtB, w, l);
    BARX();
    LGKM0();
    SCHEDB0();
    PH_MFMA(0, a0, b1, 1);
    BARX();

    // ---- phase 2 ----
    AREAD(a1, 1, cur);
    stageA64(Apanel, K, ktn, 2, nxtA, w, l);
    stageB64(Bpanel, K, ktn, 2, nxtB, w, l);
    BARX();
    LGKM0();
    SCHEDB0();
    PH_MFMA(4, a1, b0, 0);
    BARX();

    // ---- phase 3 ----
    stageA64(Apanel, K, ktn, 3, nxtA, w, l);
    stageB64(Bpanel, K, ktn, 3, nxtB, w, l);
    BARX();
    PH_MFMA(4, a1, b1, 1);
    VMCNT(4);
    BARX();
  }
#undef AREAD
#undef BREAD
#undef PH_MFMA

  float bs[4];
#pragma unroll
  for (int n = 0; n < 4; ++n) bs[n] = bias[n0 + (wc << 6) + (n << 4) + lr];
#pragma unroll
  for (int m = 0; m < 8; ++m) {
    const int gm = m0 + (wr << 7) + (m << 4) + (q << 2);
#pragma unroll
    for (int j = 0; j < 4; ++j) {
      float* Crow = C + (size_t)(gm + j) * N + n0 + (wc << 6) + lr;
#pragma unroll
      for (int n = 0; n < 4; ++n) Crow[n << 4] = acc[m][n][j] + bs[n];
    }
  }
}

// ---------------- launch ----------------

extern "C" void kernel_launch(void* const* d_in, const int* in_sizes, int n_in,
                              void* d_out, int out_size, void* d_ws, size_t ws_size,
                              hipStream_t stream) {
  const float* x = (const float*)d_in[0];    // [8,4096,1024]
  const float* Wv = (const float*)d_in[1];   // [1024,1024]
  const float* bv = (const float*)d_in[2];   // [1024]
  const float* Wo = (const float*)d_in[3];   // [1024,1024]
  const float* bo = (const float*)d_in[4];   // [1024]
  const float* nw = (const float*)d_in[5];   // [3]
  float* out = (float*)d_out;

  char* ws = (char*)d_ws;
  f16_t* WcT  = (f16_t*)(ws + (4u << 20));     // 2 MB (WcT = Wo @ Wv, [e][c])
  float* bc   = (float*)(ws + (6u << 20));     // 4 KB
  f16_t* Xavg = (f16_t*)(ws + (8u << 20));     // 64 MB

  // 1) merged prep: WcT raw-f32 (first, hidden) || bconst || xavg 32-row
  prep_kernel<<<dim3(2112), dim3(256), 0, stream>>>(
      x, Wo, Wv, bv, bo, nw, in_sizes[5], Xavg, WcT, bc);
  // 2) out[r][e] = sum_c Xavg[r][c] * WcT[e][c] + bc[e]
  gemm8p_kernel<<<dim3(512), dim3(512), 0, stream>>>(
      Xavg, WcT, out, bc, 32768, 1024, 1024);
}

// Round 20
// 134.069 us; speedup vs baseline: 1.0676x; 1.0593x over previous
//
#include <hip/hip_runtime.h>
#include <stdint.h>
#include <stddef.h>

typedef _Float16 f16_t;
typedef _Float16 f16x4 __attribute__((ext_vector_type(4)));
typedef _Float16 f16x8 __attribute__((ext_vector_type(8)));
typedef float f32x4 __attribute__((ext_vector_type(4)));
typedef float f32x8 __attribute__((ext_vector_type(8)));

#define AS_G __attribute__((address_space(1)))
#define AS_L __attribute__((address_space(3)))

__device__ __forceinline__ void gload_lds16(const void* g, void* l) {
  __builtin_amdgcn_global_load_lds((AS_G void*)g, (AS_L void*)l, 16, 0, 0);
}

#define FENCE() asm volatile("" ::: "memory")
#define BARX()                            \
  do {                                    \
    FENCE();                              \
    __builtin_amdgcn_s_barrier();         \
    FENCE();                              \
  } while (0)
#define VMCNT(n) asm volatile("s_waitcnt vmcnt(" #n ")" ::: "memory")
#define LGKM0() asm volatile("s_waitcnt lgkmcnt(0)" ::: "memory")
#if defined(__HIP_DEVICE_COMPILE__)
#define SCHEDB0() __builtin_amdgcn_sched_barrier(0)
#else
#define SCHEDB0()
#endif

// ---------------- dispatch 1: weight prep (r17 frozen) ----------------
// blocks [0,1024): Wo f32->f16 cvt; [1024,2048): Wv transpose+cvt -> WvT; [2048,3072): bconst

__global__ __launch_bounds__(256) void wprep_kernel(
    const float* __restrict__ Wo, const float* __restrict__ Wv,
    const float* __restrict__ bv, const float* __restrict__ bo,
    const float* __restrict__ nw, int Kw,
    f16_t* __restrict__ Wo_h, f16_t* __restrict__ WvT, float* __restrict__ bc) {
  __shared__ float smem[32 * 33];
  const int b = blockIdx.x;
  const int t = threadIdx.x;
  if (b < 1024) {
    const int i = b * 256 + t;
    f32x4 v = ((const f32x4*)Wo)[i];
    f16x4 o;
    o.x = (f16_t)v.x; o.y = (f16_t)v.y; o.z = (f16_t)v.z; o.w = (f16_t)v.w;
    ((f16x4*)Wo_h)[i] = o;
  } else if (b < 2048) {
    const int i = b - 1024;
    const int bx = i & 31, by = i >> 5;
    const int tx = t & 31, ty = t >> 5;
#pragma unroll
    for (int k = 0; k < 32; k += 8)
      smem[(ty + k) * 33 + tx] = Wv[(size_t)(by * 32 + ty + k) * 1024 + bx * 32 + tx];
    __syncthreads();
#pragma unroll
    for (int k = 0; k < 32; k += 8)
      WvT[(size_t)(bx * 32 + ty + k) * 1024 + by * 32 + tx] = (f16_t)smem[tx * 33 + ty + k];
  } else {
    const int e = b - 2048;
    float sw = 0.f;
    for (int k = 0; k < Kw; ++k) sw += nw[k];
    float p = 0.f;
    for (int d = t; d < 1024; d += 256) p += Wo[(size_t)e * 1024 + d] * bv[d];
    smem[t] = p;
    __syncthreads();
    for (int s = 128; s > 0; s >>= 1) {
      if (t < s) smem[t] += smem[t + s];
      __syncthreads();
    }
    if (t == 0) bc[e] = sw * smem[0] + bo[e];
  }
}

// ---------------- dispatch 2: WcT fast GEMM (hidden) || xavg 32-row (r17 frozen) ----------------

__global__ __launch_bounds__(256) void xavg_wct_kernel(
    const float* __restrict__ X, const float* __restrict__ nw,
    const f16_t* __restrict__ Wo_h, const f16_t* __restrict__ WvT,
    f16_t* __restrict__ Xavg, f16_t* __restrict__ WcT) {
  __shared__ __align__(16) f16_t sAB[2 * 128 * 32];
  const int b = blockIdx.x;
  const int tid = threadIdx.x;

  if (b < 64) {
    constexpr int K = 1024, NN = 1024;
    f16_t* sA = sAB;
    f16_t* sB = sAB + 128 * 32;
    const int l = tid & 63;
    const int w = tid >> 6;
    const int wr = w >> 1;
    const int wc = w & 1;
    const int mt = b & 7;
    const int nt = b >> 3;
    const int m0 = mt << 7;
    const int n0 = nt << 7;

    const int srow = (w << 4) + (l >> 2);
    const int scol = (l & 3) << 3;
    const size_t aoff0 = (size_t)(m0 + srow) * K + scol;
    const size_t boff0 = (size_t)(n0 + srow) * K + scol;
    f16_t* ldsA = sA + (w << 9);
    f16_t* ldsB = sB + (w << 9);

    f32x4 acc[4][4];
#pragma unroll
    for (int i = 0; i < 4; ++i)
#pragma unroll
      for (int j = 0; j < 4; ++j) acc[i][j] = f32x4{0.f, 0.f, 0.f, 0.f};

    const int ka = (l >> 4) << 3;
    const int ar = (wr << 6) + (l & 15);
    const int br = (wc << 6) + (l & 15);

    for (int kt = 0; kt < (K >> 5); ++kt) {
      const int kb = kt << 5;
      gload_lds16(Wo_h + aoff0 + kb, ldsA);
      gload_lds16(Wo_h + aoff0 + ((size_t)K << 6) + kb, ldsA + 2048);
      gload_lds16(WvT + boff0 + kb, ldsB);
      gload_lds16(WvT + boff0 + ((size_t)K << 6) + kb, ldsB + 2048);
      __syncthreads();
      f16x8 af[4], bfr[4];
#pragma unroll
      for (int m = 0; m < 4; ++m) af[m] = *(const f16x8*)(sA + ((ar + (m << 4)) << 5) + ka);
#pragma unroll
      for (int n = 0; n < 4; ++n) bfr[n] = *(const f16x8*)(sB + ((br + (n << 4)) << 5) + ka);
#pragma unroll
      for (int m = 0; m < 4; ++m)
#pragma unroll
        for (int n = 0; n < 4; ++n)
          acc[m][n] = __builtin_amdgcn_mfma_f32_16x16x32_f16(af[m], bfr[n], acc[m][n], 0, 0, 0);
      __syncthreads();
    }

    const int orow = (l >> 4) << 2;
    const int ocol = l & 15;
#pragma unroll
    for (int n = 0; n < 4; ++n) {
      const int gn = n0 + (wc << 6) + (n << 4) + ocol;
#pragma unroll
      for (int m = 0; m < 4; ++m) {
        const int gm = m0 + (wr << 6) + (m << 4) + orow;
#pragma unroll
        for (int j = 0; j < 4; ++j)
          WcT[(size_t)(gm + j) * NN + gn] = (f16_t)acc[m][n][j];
      }
    }
  } else {
    const int T = 4096, D = 1024;
    const int R0 = (b - 64) * 32;
    const int half = tid >> 7;
    const int r0 = R0 + (half << 4);
    const int bb = (r0 >> 12) << 12;
    const int be = bb + T - 1;
    const int col = (tid & 127) << 3;
    const float w0 = nw[0], w1 = nw[1], w2 = nw[2];
    const float* xb = X + (size_t)r0 * D + col;
    f32x8 pp = *(const f32x8*)(xb + ((r0 == bb) ? 0 : -D));
    f32x8 pc = *(const f32x8*)(xb);
    f16_t* ob = Xavg + (size_t)r0 * D + col;
#pragma unroll
    for (int g = 0; g < 16; ++g) {
      f32x8 pn;
      if (r0 + g == be) pn = pc;
      else pn = *(const f32x8*)(xb + (size_t)(g + 1) * D);
      f32x8 y = w0 * pp + w1 * pc + w2 * pn;
      f16x8 o;
#pragma unroll
      for (int e = 0; e < 8; ++e) o[e] = (f16_t)y[e];
      *(f16x8*)(ob + (size_t)g * D) = o;
      pp = pc;
      pc = pn;
    }
  }
}

// ---------------- dispatch 3: 256^2 GEMM, 8-phase + counted vmcnt (r15/r17 frozen) ----------------

__device__ __forceinline__ void stageA64(const f16_t* __restrict__ Ap, int K, int kt,
                                         int c, char* bufA, int w, int l) {
  const int f = w * 64 + l;
  const int sub = f >> 3, ch = f & 7;
  const int grow = ((c & 1) << 7) + ((c >> 1) << 6) + sub;
  const int gcol = (kt << 6) + ((ch ^ (sub & 7)) << 3);
  gload_lds16(Ap + (size_t)grow * K + gcol, bufA + c * 8192 + w * 1024);
}

__device__ __forceinline__ void stageB64(const f16_t* __restrict__ Bp, int K, int kt,
                                         int c, char* bufB, int w, int l) {
  const int f = w * 64 + l;
  const int rr = f >> 3, ch = f & 7;
  const int wc = ((c & 1) << 1) + (rr >> 5);
  const int sub = rr & 31;
  const int grow = (wc << 6) + ((c >> 1) << 5) + sub;
  const int gcol = (kt << 6) + ((ch ^ (sub & 7)) << 3);
  gload_lds16(Bp + (size_t)grow * K + gcol, bufB + c * 8192 + w * 1024);
}

__global__ __launch_bounds__(512, 2) void gemm8p_kernel(const f16_t* __restrict__ A,
                                                        const f16_t* __restrict__ Bt,
                                                        float* __restrict__ C,
                                                        const float* __restrict__ bias,
                                                        int M, int N, int K) {
  __shared__ __align__(16) char lds[2 * 65536];
  const int tid = threadIdx.x;
  const int l = tid & 63;
  const int w = tid >> 6;
  const int wr = w >> 2;
  const int wc = w & 3;
  const int lr = l & 15;
  const int q = l >> 4;

  const int cpx = (int)gridDim.x >> 3;
  const int swzb = ((int)blockIdx.x & 7) * cpx + ((int)blockIdx.x >> 3);
  const int nNT = N >> 8;
  const int mt = swzb / nNT;
  const int nt = swzb % nNT;
  const int m0 = mt << 8;
  const int n0 = nt << 8;

  const f16_t* Apanel = A + (size_t)m0 * K;
  const f16_t* Bpanel = Bt + (size_t)n0 * K;

  const int x7 = lr & 7;

  f32x4 acc[8][4];
#pragma unroll
  for (int m = 0; m < 8; ++m)
#pragma unroll
    for (int n = 0; n < 4; ++n) acc[m][n] = f32x4{0.f, 0.f, 0.f, 0.f};

  const int nT = K >> 6;

  f16x8 a0[4][2], a1[4][2], b0[2][2], b1[2][2];

#define AREAD(DST, MH, BUF)                                                     \
  do {                                                                          \
    const char* p_ = (BUF) + (((MH)*2 + wr) << 13);                             \
    _Pragma("unroll") for (int mm = 0; mm < 4; ++mm)                            \
      _Pragma("unroll") for (int kk = 0; kk < 2; ++kk)                          \
        DST[mm][kk] = *(const f16x8*)(p_ + ((mm * 16 + lr) << 7) +              \
                                      ((((kk << 2) + q) ^ x7) << 4));           \
  } while (0)
#define BREAD(DST, NP, BUF)                                                     \
  do {                                                                          \
    const char* p_ = (BUF) + 32768 + ((((NP) << 2) + wc) << 12);                \
    _Pragma("unroll") for (int nn = 0; nn < 2; ++nn)                            \
      _Pragma("unroll") for (int kk = 0; kk < 2; ++kk)                          \
        DST[nn][kk] = *(const f16x8*)(p_ + ((nn * 16 + lr) << 7) +              \
                                      ((((kk << 2) + q) ^ x7) << 4));           \
  } while (0)
#define PH_MFMA(MB, AR, BR, NPB)                                                \
  do {                                                                          \
    __builtin_amdgcn_s_setprio(1);                                              \
    _Pragma("unroll") for (int mm = 0; mm < 4; ++mm)                            \
      _Pragma("unroll") for (int nn = 0; nn < 2; ++nn) {                        \
        acc[(MB) + mm][(NPB)*2 + nn] = __builtin_amdgcn_mfma_f32_16x16x32_f16(  \
            AR[mm][0], BR[nn][0], acc[(MB) + mm][(NPB)*2 + nn], 0, 0, 0);       \
        acc[(MB) + mm][(NPB)*2 + nn] = __builtin_amdgcn_mfma_f32_16x16x32_f16(  \
            AR[mm][1], BR[nn][1], acc[(MB) + mm][(NPB)*2 + nn], 0, 0, 0);       \
      }                                                                         \
    __builtin_amdgcn_s_setprio(0);                                              \
  } while (0)

  stageA64(Apanel, K, 0, 0, lds, w, l);
  stageB64(Bpanel, K, 0, 0, lds + 32768, w, l);
  stageA64(Apanel, K, 0, 1, lds, w, l);
  stageB64(Bpanel, K, 0, 1, lds + 32768, w, l);
  stageA64(Apanel, K, 0, 2, lds, w, l);
  stageB64(Bpanel, K, 0, 2, lds + 32768, w, l);
  stageA64(Apanel, K, 0, 3, lds, w, l);
  stageB64(Bpanel, K, 0, 3, lds + 32768, w, l);
  VMCNT(4);
  BARX();

  for (int tt = 0; tt < nT; ++tt) {
    char* cur = lds + (tt & 1) * 65536;
    char* nxtA = lds + ((tt + 1) & 1) * 65536;
    char* nxtB = nxtA + 32768;
    const int ktn = (tt + 1) < nT ? (tt + 1) : (nT - 1);

    // ---- phase 0 ----
    AREAD(a0, 0, cur);
    BREAD(b0, 0, cur);
    stageA64(Apanel, K, ktn, 0, nxtA, w, l);
    stageB64(Bpanel, K, ktn, 0, nxtB, w, l);
    VMCNT(2);
    BARX();
    LGKM0();
    SCHEDB0();
    PH_MFMA(0, a0, b0, 0);
    BARX();

    // ---- phase 1 ----
    BREAD(b1, 1, cur);
    stageA64(Apanel, K, ktn, 1, nxtA, w, l);
    stageB64(Bpanel, K, ktn, 1, nxtB, w, l);
    BARX();
    LGKM0();
    SCHEDB0();
    PH_MFMA(0, a0, b1, 1);
    BARX();

    // ---- phase 2 ----
    AREAD(a1, 1, cur);
    stageA64(Apanel, K, ktn, 2, nxtA, w, l);
    stageB64(Bpanel, K, ktn, 2, nxtB, w, l);
    BARX();
    LGKM0();
    SCHEDB0();
    PH_MFMA(4, a1, b0, 0);
    BARX();

    // ---- phase 3 ----
    stageA64(Apanel, K, ktn, 3, nxtA, w, l);
    stageB64(Bpanel, K, ktn, 3, nxtB, w, l);
    BARX();
    PH_MFMA(4, a1, b1, 1);
    VMCNT(4);
    BARX();
  }
#undef AREAD
#undef BREAD
#undef PH_MFMA

  float bs[4];
#pragma unroll
  for (int n = 0; n < 4; ++n) bs[n] = bias[n0 + (wc << 6) + (n << 4) + lr];
#pragma unroll
  for (int m = 0; m < 8; ++m) {
    const int gm = m0 + (wr << 7) + (m << 4) + (q << 2);
#pragma unroll
    for (int j = 0; j < 4; ++j) {
      float* Crow = C + (size_t)(gm + j) * N + n0 + (wc << 6) + lr;
#pragma unroll
      for (int n = 0; n < 4; ++n) Crow[n << 4] = acc[m][n][j] + bs[n];
    }
  }
}

// ---------------- launch ----------------

extern "C" void kernel_launch(void* const* d_in, const int* in_sizes, int n_in,
                              void* d_out, int out_size, void* d_ws, size_t ws_size,
                              hipStream_t stream) {
  const float* x = (const float*)d_in[0];    // [8,4096,1024]
  const float* Wv = (const float*)d_in[1];   // [1024,1024]
  const float* bv = (const float*)d_in[2];   // [1024]
  const float* Wo = (const float*)d_in[3];   // [1024,1024]
  const float* bo = (const float*)d_in[4];   // [1024]
  const float* nw = (const float*)d_in[5];   // [3]
  float* out = (float*)d_out;

  char* ws = (char*)d_ws;
  f16_t* Wo_h = (f16_t*)(ws);                  // 2 MB
  f16_t* WvT  = (f16_t*)(ws + (2u << 20));     // 2 MB
  f16_t* WcT  = (f16_t*)(ws + (4u << 20));     // 2 MB (WcT = Wo @ Wv, [e][c])
  float* bc   = (float*)(ws + (6u << 20));     // 4 KB
  f16_t* Xavg = (f16_t*)(ws + (8u << 20));     // 64 MB

  // 1) weight prep: Wo cvt || WvT transpose || bconst (~16 MB, fast)
  wprep_kernel<<<dim3(3072), dim3(256), 0, stream>>>(
      Wo, Wv, bv, bo, nw, in_sizes[5], Wo_h, WvT, bc);
  // 2) WcT fast-path GEMM (blocks 0-63, hidden) || xavg 32-row (blocks 64-1087)
  xavg_wct_kernel<<<dim3(1088), dim3(256), 0, stream>>>(
      x, nw, Wo_h, WvT, Xavg, WcT);
  // 3) out[r][e] = sum_c Xavg[r][c] * WcT[e][c] + bc[e]
  gemm8p_kernel<<<dim3(512), dim3(512), 0, stream>>>(
      Xavg, WcT, out, bc, 32768, 1024, 1024);
}